// Round 3
// baseline (265.588 us; speedup 1.0000x reference)
//
#include <hip/hip_runtime.h>
#include <hip/hip_bf16.h>

#define N_NODES_C 100000
#define NSCAN     102400      // N padded to 25 * 4096 for the scan
#define SCAN_BS   1024        // threads per scan block (4 elems each -> 4096/block)
#define NB_SCAN   (NSCAN / (SCAN_BS * 4))   // 25 blocks

// ---------------------------------------------------------------------------
// CSR build: histogram -> block scan -> partials scan -> add -> fill
// ---------------------------------------------------------------------------
__global__ __launch_bounds__(256) void edge_hist(
    const int* __restrict__ dst, int* __restrict__ counts, int n_edges)
{
    int i = blockIdx.x * 256 + threadIdx.x;
    int b4 = i * 4;
    if (b4 + 3 < n_edges) {
        int4 d = reinterpret_cast<const int4*>(dst)[i];
        atomicAdd(&counts[d.x], 1);
        atomicAdd(&counts[d.y], 1);
        atomicAdd(&counts[d.z], 1);
        atomicAdd(&counts[d.w], 1);
    } else {
        for (int e = b4; e < n_edges; ++e) atomicAdd(&counts[dst[e]], 1);
    }
}

__global__ __launch_bounds__(SCAN_BS) void scan_block(
    const int* __restrict__ counts, int* __restrict__ offsets,
    int* __restrict__ partials)
{
    __shared__ int sd[2][SCAN_BS];
    int t = threadIdx.x, b = blockIdx.x;
    int4 c = reinterpret_cast<const int4*>(counts)[b * SCAN_BS + t];
    int tot = c.x + c.y + c.z + c.w;
    sd[0][t] = tot;
    __syncthreads();
    int pin = 0;
    #pragma unroll
    for (int off = 1; off < SCAN_BS; off <<= 1) {
        int v = sd[pin][t];
        if (t >= off) v += sd[pin][t - off];
        sd[pin ^ 1][t] = v;
        pin ^= 1;
        __syncthreads();
    }
    int incl = sd[pin][t];      // inclusive scan of per-thread sums
    int excl = incl - tot;
    int4 o;
    o.x = excl;
    o.y = excl + c.x;
    o.z = excl + c.x + c.y;
    o.w = excl + c.x + c.y + c.z;
    reinterpret_cast<int4*>(offsets)[b * SCAN_BS + t] = o;
    if (t == SCAN_BS - 1) partials[b] = incl;
}

__global__ __launch_bounds__(64) void scan_partials(int* __restrict__ partials, int nb)
{
    int t = threadIdx.x;
    int orig = (t < nb) ? partials[t] : 0;
    int v = orig;
    #pragma unroll
    for (int off = 1; off < 64; off <<= 1) {
        int u = __shfl_up(v, off, 64);
        if (t >= off) v += u;
    }
    if (t < nb) partials[t] = v - orig;   // exclusive
}

__global__ __launch_bounds__(256) void scan_add(
    int* __restrict__ offsets, int* __restrict__ cursors,
    const int* __restrict__ partials)
{
    int i = blockIdx.x * 256 + threadIdx.x;
    if (i < NSCAN) {
        int v = offsets[i] + partials[i >> 12];   // i/4096
        offsets[i] = v;
        cursors[i] = v;
    }
}

__global__ __launch_bounds__(256) void edge_fill(
    const int* __restrict__ src, const int* __restrict__ dst,
    int* __restrict__ cursors, int* __restrict__ edge_src, int n_edges)
{
    int i = blockIdx.x * 256 + threadIdx.x;
    int b4 = i * 4;
    if (b4 + 3 < n_edges) {
        int4 s = reinterpret_cast<const int4*>(src)[i];
        int4 d = reinterpret_cast<const int4*>(dst)[i];
        int p0 = atomicAdd(&cursors[d.x], 1); edge_src[p0] = s.x;
        int p1 = atomicAdd(&cursors[d.y], 1); edge_src[p1] = s.y;
        int p2 = atomicAdd(&cursors[d.z], 1); edge_src[p2] = s.z;
        int p3 = atomicAdd(&cursors[d.w], 1); edge_src[p3] = s.w;
    } else {
        for (int e = b4; e < n_edges; ++e) {
            int pos = atomicAdd(&cursors[dst[e]], 1);
            edge_src[pos] = src[e];
        }
    }
}

// ---------------------------------------------------------------------------
// Fused gather-mean + GEMM.
// Block: 256 threads, 64 nodes. LDS: X tile only (32KB, swizzled float4).
// W streams from global in the GEMM loop (L1-resident, broadcast across lanes).
// x[r][0:16)  = h_dst row           (k4 = 0..15)
// x[r][16:32) = mean of neighbors   (k4 = 16..31), gathered via CSR
// out[n][o] = bias[o] + sum_k x[n][k] * W[o][k]
// ---------------------------------------------------------------------------
__global__ __launch_bounds__(256, 4) void sage_fused(
    const float* __restrict__ h_src,
    const float* __restrict__ h_dst,
    const int*   __restrict__ offsets,
    const int*   __restrict__ edge_src,
    const float* __restrict__ weight,   // [64][128] row-major
    const float* __restrict__ bias,     // [64]
    float*       __restrict__ out,      // [N][64]
    int n_nodes)
{
    __shared__ float4 x4[64 * 32];   // x4[r][k4] at r*32 + ((k4 + r) & 31)

    const int t    = threadIdx.x;
    const int base = blockIdx.x * 64;

    // stage h_dst (cols 0..15)
    #pragma unroll
    for (int q = 0; q < 4; ++q) {
        int idx = t + q * 256;        // 0..1023
        int r   = idx >> 4;
        int k4  = idx & 15;
        int g   = base + r;
        float4 xv = make_float4(0.f, 0.f, 0.f, 0.f);
        if (g < n_nodes)
            xv = reinterpret_cast<const float4*>(h_dst)[(size_t)g * 16 + k4];
        x4[r * 32 + ((k4 + r) & 31)] = xv;
    }

    // gather neighbor mean (cols 16..31): 4 threads per node, 2-edge unroll
    {
        const int j = t & 3;          // float4 lane group within row
        const int r = t >> 2;         // node within tile (0..63)
        const int g = base + r;
        float4 a0 = make_float4(0.f, 0.f, 0.f, 0.f);
        float4 a1 = a0, a2 = a0, a3 = a0;
        float invd = 0.f;
        if (g < n_nodes) {
            int e0 = offsets[g];
            int e1 = offsets[g + 1];
            for (int e = e0; e < e1; e += 2) {
                int s0 = edge_src[e];
                int s1 = (e + 1 < e1) ? edge_src[e + 1] : -1;
                const float4* row0 = reinterpret_cast<const float4*>(h_src) + (size_t)s0 * 16;
                float4 v0 = row0[j +  0];
                float4 v1 = row0[j +  4];
                float4 v2 = row0[j +  8];
                float4 v3 = row0[j + 12];
                if (s1 >= 0) {
                    const float4* row1 = reinterpret_cast<const float4*>(h_src) + (size_t)s1 * 16;
                    float4 u0 = row1[j +  0];
                    float4 u1 = row1[j +  4];
                    float4 u2 = row1[j +  8];
                    float4 u3 = row1[j + 12];
                    v0.x += u0.x; v0.y += u0.y; v0.z += u0.z; v0.w += u0.w;
                    v1.x += u1.x; v1.y += u1.y; v1.z += u1.z; v1.w += u1.w;
                    v2.x += u2.x; v2.y += u2.y; v2.z += u2.z; v2.w += u2.w;
                    v3.x += u3.x; v3.y += u3.y; v3.z += u3.z; v3.w += u3.w;
                }
                a0.x += v0.x; a0.y += v0.y; a0.z += v0.z; a0.w += v0.w;
                a1.x += v1.x; a1.y += v1.y; a1.z += v1.z; a1.w += v1.w;
                a2.x += v2.x; a2.y += v2.y; a2.z += v2.z; a2.w += v2.w;
                a3.x += v3.x; a3.y += v3.y; a3.z += v3.z; a3.w += v3.w;
            }
            int degv = e1 - e0;
            invd = 1.0f / (float)(degv > 1 ? degv : 1);
        }
        a0.x *= invd; a0.y *= invd; a0.z *= invd; a0.w *= invd;
        a1.x *= invd; a1.y *= invd; a1.z *= invd; a1.w *= invd;
        a2.x *= invd; a2.y *= invd; a2.z *= invd; a2.w *= invd;
        a3.x *= invd; a3.y *= invd; a3.z *= invd; a3.w *= invd;
        x4[r * 32 + (((16 + j +  0) + r) & 31)] = a0;
        x4[r * 32 + (((16 + j +  4) + r) & 31)] = a1;
        x4[r * 32 + (((16 + j +  8) + r) & 31)] = a2;
        x4[r * 32 + (((16 + j + 12) + r) & 31)] = a3;
    }
    __syncthreads();

    // GEMM: thread tile = 4 nodes x 4 outs; W streamed from global (L1)
    const int m  = t & 15;    // out-group: o0 = 4m
    const int r0 = t >> 4;    // node base: rows r0 + 16*i
    const int o0 = m * 4;

    const float4* w4g = reinterpret_cast<const float4*>(weight);
    float4 bv = reinterpret_cast<const float4*>(bias)[m];

    float acc[4][4];
    #pragma unroll
    for (int i = 0; i < 4; ++i) {
        acc[i][0] = bv.x; acc[i][1] = bv.y; acc[i][2] = bv.z; acc[i][3] = bv.w;
    }

    #pragma unroll 4
    for (int k4 = 0; k4 < 32; ++k4) {
        float4 wv[4];
        #pragma unroll
        for (int jj = 0; jj < 4; ++jj)
            wv[jj] = w4g[(o0 + jj) * 32 + k4];
        #pragma unroll
        for (int i = 0; i < 4; ++i) {
            int r = r0 + 16 * i;
            float4 xv = x4[r * 32 + ((k4 + r) & 31)];
            #pragma unroll
            for (int jj = 0; jj < 4; ++jj) {
                acc[i][jj] += xv.x * wv[jj].x + xv.y * wv[jj].y
                            + xv.z * wv[jj].z + xv.w * wv[jj].w;
            }
        }
    }

    #pragma unroll
    for (int i = 0; i < 4; ++i) {
        int g = base + r0 + 16 * i;
        if (g < n_nodes) {
            float4 ov = make_float4(acc[i][0], acc[i][1], acc[i][2], acc[i][3]);
            reinterpret_cast<float4*>(out)[(size_t)g * 16 + m] = ov;
        }
    }
}

// ---------------------------------------------------------------------------
extern "C" void kernel_launch(void* const* d_in, const int* in_sizes, int n_in,
                              void* d_out, int out_size, void* d_ws, size_t ws_size,
                              hipStream_t stream)
{
    const float* h_src  = (const float*)d_in[0];
    const float* h_dst  = (const float*)d_in[1];
    const int*   src    = (const int*)d_in[2];
    const int*   dst    = (const int*)d_in[3];
    const float* weight = (const float*)d_in[4];
    const float* bias   = (const float*)d_in[5];
    float*       out    = (float*)d_out;

    const int n_edges = in_sizes[2];

    // workspace layout (ints)
    int* counts   = (int*)d_ws;            // NSCAN
    int* offsets  = counts   + NSCAN;      // NSCAN  (offsets[N] valid)
    int* cursors  = offsets  + NSCAN;      // NSCAN
    int* partials = cursors  + NSCAN;      // 64
    int* edge_src = partials + 64;         // n_edges

    // zero the histogram (ws is poisoned; everything else is fully rewritten)
    hipMemsetAsync(counts, 0, NSCAN * sizeof(int), stream);

    int nbE4 = ((n_edges + 3) / 4 + 255) / 256;
    edge_hist<<<nbE4, 256, 0, stream>>>(dst, counts, n_edges);
    scan_block<<<NB_SCAN, SCAN_BS, 0, stream>>>(counts, offsets, partials);
    scan_partials<<<1, 64, 0, stream>>>(partials, NB_SCAN);
    scan_add<<<NSCAN / 256, 256, 0, stream>>>(offsets, cursors, partials);
    edge_fill<<<nbE4, 256, 0, stream>>>(src, dst, cursors, edge_src, n_edges);

    sage_fused<<<(N_NODES_C + 63) / 64, 256, 0, stream>>>(
        h_src, h_dst, offsets, edge_src, weight, bias, out, N_NODES_C);
}

// Round 4
// 232.323 us; speedup vs baseline: 1.1432x; 1.1432x over previous
//
#include <hip/hip_runtime.h>
#include <hip/hip_bf16.h>

#define N_NODES_C 100000
#define NSCAN     102400      // N padded to 25 * 4096 for the scan
#define SCAN_BS   1024        // threads per scan block (4 elems each -> 4096/block)
#define NB_SCAN   (NSCAN / (SCAN_BS * 4))   // 25 blocks

// ---------------------------------------------------------------------------
// CSR build: histogram(+rank) -> block scan -> scan_add(inline partials) -> fill
// ---------------------------------------------------------------------------
__global__ __launch_bounds__(256) void edge_hist(
    const int* __restrict__ dst, int* __restrict__ counts,
    int* __restrict__ rank, int n_edges)
{
    int i = blockIdx.x * 256 + threadIdx.x;
    int b4 = i * 4;
    if (b4 + 3 < n_edges) {
        int4 d = reinterpret_cast<const int4*>(dst)[i];
        int4 rk;
        rk.x = atomicAdd(&counts[d.x], 1);
        rk.y = atomicAdd(&counts[d.y], 1);
        rk.z = atomicAdd(&counts[d.z], 1);
        rk.w = atomicAdd(&counts[d.w], 1);
        reinterpret_cast<int4*>(rank)[i] = rk;
    } else {
        for (int e = b4; e < n_edges; ++e)
            rank[e] = atomicAdd(&counts[dst[e]], 1);
    }
}

__global__ __launch_bounds__(SCAN_BS) void scan_block(
    const int* __restrict__ counts, int* __restrict__ offsets,
    int* __restrict__ partials)
{
    __shared__ int sd[2][SCAN_BS];
    int t = threadIdx.x, b = blockIdx.x;
    int4 c = reinterpret_cast<const int4*>(counts)[b * SCAN_BS + t];
    int tot = c.x + c.y + c.z + c.w;
    sd[0][t] = tot;
    __syncthreads();
    int pin = 0;
    #pragma unroll
    for (int off = 1; off < SCAN_BS; off <<= 1) {
        int v = sd[pin][t];
        if (t >= off) v += sd[pin][t - off];
        sd[pin ^ 1][t] = v;
        pin ^= 1;
        __syncthreads();
    }
    int incl = sd[pin][t];      // inclusive scan of per-thread sums
    int excl = incl - tot;
    int4 o;
    o.x = excl;
    o.y = excl + c.x;
    o.z = excl + c.x + c.y;
    o.w = excl + c.x + c.y + c.z;
    reinterpret_cast<int4*>(offsets)[b * SCAN_BS + t] = o;
    if (t == SCAN_BS - 1) partials[b] = incl;
}

// one block per scan_block tile; thread 0 sums the (<=24) preceding partials
__global__ __launch_bounds__(SCAN_BS) void scan_add(
    int* __restrict__ offsets, const int* __restrict__ partials)
{
    __shared__ int base_s;
    int b = blockIdx.x;
    if (threadIdx.x == 0) {
        int s = 0;
        for (int i = 0; i < b; ++i) s += partials[i];
        base_s = s;
    }
    __syncthreads();
    int i = b * SCAN_BS + threadIdx.x;
    int4 v = reinterpret_cast<int4*>(offsets)[i];
    v.x += base_s; v.y += base_s; v.z += base_s; v.w += base_s;
    reinterpret_cast<int4*>(offsets)[i] = v;
}

__global__ __launch_bounds__(256) void edge_fill(
    const int* __restrict__ src, const int* __restrict__ dst,
    const int* __restrict__ rank, const int* __restrict__ offsets,
    int* __restrict__ edge_src, int n_edges)
{
    int i = blockIdx.x * 256 + threadIdx.x;
    int b4 = i * 4;
    if (b4 + 3 < n_edges) {
        int4 s  = reinterpret_cast<const int4*>(src)[i];
        int4 d  = reinterpret_cast<const int4*>(dst)[i];
        int4 rk = reinterpret_cast<const int4*>(rank)[i];
        edge_src[offsets[d.x] + rk.x] = s.x;
        edge_src[offsets[d.y] + rk.y] = s.y;
        edge_src[offsets[d.z] + rk.z] = s.z;
        edge_src[offsets[d.w] + rk.w] = s.w;
    } else {
        for (int e = b4; e < n_edges; ++e)
            edge_src[offsets[dst[e]] + rank[e]] = src[e];
    }
}

// ---------------------------------------------------------------------------
// Fused gather-mean + GEMM.
// Block: 256 threads, 64 nodes. LDS: X tile only (32KB, swizzled float4).
// Gather: 16 threads per node (one float4 column each), 4-edge unroll ->
// 4 independent loads in flight at ~1 acc reg. 4 passes cover 64 nodes.
// W streams from global in the GEMM loop (L1-resident, 4-lane dedup).
// ---------------------------------------------------------------------------
__global__ __launch_bounds__(256) void sage_fused(
    const float* __restrict__ h_src,
    const float* __restrict__ h_dst,
    const int*   __restrict__ offsets,
    const int*   __restrict__ edge_src,
    const float* __restrict__ weight,   // [64][128] row-major
    const float* __restrict__ bias,     // [64]
    float*       __restrict__ out,      // [N][64]
    int n_nodes)
{
    __shared__ float4 x4[64 * 32];   // x4[r][k4] at r*32 + ((k4 + r) & 31)

    const int t    = threadIdx.x;
    const int base = blockIdx.x * 64;
    const float4* hs4 = reinterpret_cast<const float4*>(h_src);

    // stage h_dst (cols 0..15)
    #pragma unroll
    for (int q = 0; q < 4; ++q) {
        int idx = t + q * 256;        // 0..1023
        int r   = idx >> 4;
        int k4  = idx & 15;
        int g   = base + r;
        float4 xv = make_float4(0.f, 0.f, 0.f, 0.f);
        if (g < n_nodes)
            xv = reinterpret_cast<const float4*>(h_dst)[(size_t)g * 16 + k4];
        x4[r * 32 + ((k4 + r) & 31)] = xv;
    }

    // gather neighbor mean (cols 16..31): 16 threads/node, 4-edge unroll
    {
        const int j    = t & 15;      // float4 column within row
        const int rloc = t >> 4;      // 0..15
        #pragma unroll
        for (int p = 0; p < 4; ++p) {
            const int r = p * 16 + rloc;
            const int g = base + r;
            float4 acc = make_float4(0.f, 0.f, 0.f, 0.f);
            float invd = 0.f;
            if (g < n_nodes) {
                int e0 = offsets[g];
                int e1 = offsets[g + 1];
                int e  = e0;
                for (; e + 4 <= e1; e += 4) {
                    int s0 = edge_src[e + 0];
                    int s1 = edge_src[e + 1];
                    int s2 = edge_src[e + 2];
                    int s3 = edge_src[e + 3];
                    float4 v0 = hs4[(size_t)s0 * 16 + j];
                    float4 v1 = hs4[(size_t)s1 * 16 + j];
                    float4 v2 = hs4[(size_t)s2 * 16 + j];
                    float4 v3 = hs4[(size_t)s3 * 16 + j];
                    acc.x += (v0.x + v1.x) + (v2.x + v3.x);
                    acc.y += (v0.y + v1.y) + (v2.y + v3.y);
                    acc.z += (v0.z + v1.z) + (v2.z + v3.z);
                    acc.w += (v0.w + v1.w) + (v2.w + v3.w);
                }
                for (; e < e1; ++e) {
                    int s = edge_src[e];
                    float4 v = hs4[(size_t)s * 16 + j];
                    acc.x += v.x; acc.y += v.y; acc.z += v.z; acc.w += v.w;
                }
                int degv = e1 - e0;
                invd = 1.0f / (float)(degv > 1 ? degv : 1);
            }
            acc.x *= invd; acc.y *= invd; acc.z *= invd; acc.w *= invd;
            x4[r * 32 + (((16 + j) + r) & 31)] = acc;
        }
    }
    __syncthreads();

    // GEMM: thread tile = 4 nodes x 4 outs; W streamed from global (L1)
    const int m  = t & 15;    // out-group: o0 = 4m
    const int r0 = t >> 4;    // node base: rows r0 + 16*i
    const int o0 = m * 4;

    const float4* w4g = reinterpret_cast<const float4*>(weight);
    float4 bv = reinterpret_cast<const float4*>(bias)[m];

    float acc[4][4];
    #pragma unroll
    for (int i = 0; i < 4; ++i) {
        acc[i][0] = bv.x; acc[i][1] = bv.y; acc[i][2] = bv.z; acc[i][3] = bv.w;
    }

    #pragma unroll 4
    for (int k4 = 0; k4 < 32; ++k4) {
        float4 wv[4];
        #pragma unroll
        for (int jj = 0; jj < 4; ++jj)
            wv[jj] = w4g[(o0 + jj) * 32 + k4];
        #pragma unroll
        for (int i = 0; i < 4; ++i) {
            int r = r0 + 16 * i;
            float4 xv = x4[r * 32 + ((k4 + r) & 31)];
            #pragma unroll
            for (int jj = 0; jj < 4; ++jj) {
                acc[i][jj] += xv.x * wv[jj].x + xv.y * wv[jj].y
                            + xv.z * wv[jj].z + xv.w * wv[jj].w;
            }
        }
    }

    #pragma unroll
    for (int i = 0; i < 4; ++i) {
        int g = base + r0 + 16 * i;
        if (g < n_nodes) {
            float4 ov = make_float4(acc[i][0], acc[i][1], acc[i][2], acc[i][3]);
            reinterpret_cast<float4*>(out)[(size_t)g * 16 + m] = ov;
        }
    }
}

// ---------------------------------------------------------------------------
extern "C" void kernel_launch(void* const* d_in, const int* in_sizes, int n_in,
                              void* d_out, int out_size, void* d_ws, size_t ws_size,
                              hipStream_t stream)
{
    const float* h_src  = (const float*)d_in[0];
    const float* h_dst  = (const float*)d_in[1];
    const int*   src    = (const int*)d_in[2];
    const int*   dst    = (const int*)d_in[3];
    const float* weight = (const float*)d_in[4];
    const float* bias   = (const float*)d_in[5];
    float*       out    = (float*)d_out;

    const int n_edges = in_sizes[2];

    // workspace layout (ints); rank base is 16B-aligned
    int* counts   = (int*)d_ws;            // NSCAN
    int* offsets  = counts   + NSCAN;      // NSCAN  (offsets[N] valid)
    int* partials = offsets  + NSCAN;      // 64
    int* rank     = partials + 64;         // n_edges (16B aligned: 2*NSCAN+64 ints)
    int* edge_src = rank     + n_edges;    // n_edges

    // zero the histogram (ws is poisoned; everything else is fully rewritten)
    hipMemsetAsync(counts, 0, NSCAN * sizeof(int), stream);

    int nbE4 = ((n_edges + 3) / 4 + 255) / 256;
    edge_hist<<<nbE4, 256, 0, stream>>>(dst, counts, rank, n_edges);
    scan_block<<<NB_SCAN, SCAN_BS, 0, stream>>>(counts, offsets, partials);
    scan_add<<<NB_SCAN, SCAN_BS, 0, stream>>>(offsets, partials);
    edge_fill<<<nbE4, 256, 0, stream>>>(src, dst, rank, offsets, edge_src, n_edges);

    sage_fused<<<(N_NODES_C + 63) / 64, 256, 0, stream>>>(
        h_src, h_dst, offsets, edge_src, weight, bias, out, N_NODES_C);
}